// Round 1
// baseline (403.584 us; speedup 1.0000x reference)
//
#include <hip/hip_runtime.h>
#include <hip/hip_cooperative_groups.h>

namespace cg = cooperative_groups;

#define KHOPS  8
#define BS     1024            // threads per block
#define MAXL   50176           // max links (LDS tables sized for this)
#define HWORDS (MAXL / 2)      // u16-pair histogram words
#define GRID   256             // 1 block/CU, all co-resident (150 KB LDS)
#define NXCD   8
#define RPQ    (GRID / NXCD)   // 32 replicas per sub-lane in merge
#define TSCALE  2048.0f        // traffic deposit fixed-point scale (Q11)
#define XSCALE  131072.0f      // X_l fixed-point scale (Q17)

typedef unsigned char  u8;
typedef unsigned short u16;
typedef unsigned int   u32;

// deposit helper: packed u16-pair histogram, ds_add_u32
__device__ __forceinline__ void deposit(u32* h, u32 link, float t) {
    atomicAdd(&h[link >> 1], __float2uint_rn(t * TSCALE) << ((link & 1) << 4));
}

// ---------------------------------------------------------------------------
// Single persistent cooperative kernel.
//   - edges (8 hops x 4 paths, packed u16) + A live in REGISTERS for the
//     whole kernel: e16/A global arrays are gone (saves 64 MB of round trips)
//   - per iteration: LDS scatter -> flush Trep -> grid.sync ->
//     fused merge+link_update (8-lane butterfly over 256 replicas) -> grid.sync
//   - final gather straight from registers + LDS X_l table
// ---------------------------------------------------------------------------
__global__ __launch_bounds__(BS) void fused_kernel(
        const float* __restrict__ P,         // (n_paths,3)
        const float* __restrict__ L,         // (n_links,1)
        const int*   __restrict__ pl_edges,  // (KHOPS,n_paths)
        u32*   __restrict__ Trep,            // [GRID][nwords]
        u8*    __restrict__ bpq,             // (n_links) Q8
        u16*   __restrict__ xq,              // (n_links) Q17
        float* __restrict__ res,             // (n_paths,)
        float* __restrict__ out_links,       // (n_links,3)
        int n_paths, int n_links, int nwords) {
    __shared__ u32 h[HWORDS];                // 100352 B
    __shared__ u8  bpl[MAXL];                // 50176 B  (total 150528 <= 160K)
    const int tid = threadIdx.x;
    cg::grid_group grid = cg::this_grid();

    // ---- persistent per-thread path state (n_paths % 4 == 0 here) ----
    const int p = (blockIdx.x * BS + tid) * 4;
    const bool act = (p + 3 < n_paths);
    uint2 ep[KHOPS];
    float a0 = 0.f, a1 = 0.f, a2 = 0.f, a3 = 0.f;
    if (act) {
#pragma unroll
        for (int k = 0; k < KHOPS; ++k) {
            int4 e4 = *(const int4*)&pl_edges[k * n_paths + p];   // coalesced
            ep[k].x = (u32)(e4.x - n_paths) | ((u32)(e4.y - n_paths) << 16);
            ep[k].y = (u32)(e4.z - n_paths) | ((u32)(e4.w - n_paths) << 16);
        }
        float4 q0 = *(const float4*)&P[3 * p];        // A = P[:,1]
        float4 q1 = *(const float4*)&P[3 * p + 4];
        float4 q2 = *(const float4*)&P[3 * p + 8];
        a0 = q0.y; a1 = q1.x; a2 = q1.w; a3 = q2.z;
    }

    u32* Tmine = Trep + (size_t)blockIdx.x * nwords;

    for (int it = 0; it < 3; ++it) {
        // ---------------- scatter into LDS histogram ----------------
        for (int i = tid; i < nwords; i += BS) h[i] = 0u;
        if (it > 0)
            for (int i = tid; i < n_links; i += BS) bpl[i] = bpq[i];
        __syncthreads();

        if (act) {
            float t0 = a0, t1 = a1, t2 = a2, t3 = a3;
            if (it == 0) {
#pragma unroll
                for (int k = 0; k < KHOPS; ++k) {     // bp == 0.5 constant
                    deposit(h, ep[k].x & 0xffffu, t0);
                    deposit(h, ep[k].x >> 16,     t1);
                    deposit(h, ep[k].y & 0xffffu, t2);
                    deposit(h, ep[k].y >> 16,     t3);
                    t0 *= 0.5f; t1 *= 0.5f; t2 *= 0.5f; t3 *= 0.5f;
                }
            } else {
#pragma unroll
                for (int k = 0; k < KHOPS; ++k) {
                    u32 l0 = ep[k].x & 0xffffu, l1 = ep[k].x >> 16;
                    u32 l2 = ep[k].y & 0xffffu, l3 = ep[k].y >> 16;
                    deposit(h, l0, t0);
                    deposit(h, l1, t1);
                    deposit(h, l2, t2);
                    deposit(h, l3, t3);
                    t0 *= (float)(256 - (int)bpl[l0]) * (1.0f / 256.0f);
                    t1 *= (float)(256 - (int)bpl[l1]) * (1.0f / 256.0f);
                    t2 *= (float)(256 - (int)bpl[l2]) * (1.0f / 256.0f);
                    t3 *= (float)(256 - (int)bpl[l3]) * (1.0f / 256.0f);
                }
            }
        }
        __syncthreads();
        for (int i = tid; i < nwords; i += BS) Tmine[i] = h[i];

        grid.sync();    // Trep visible device-wide

        // ------------- fused merge + link update -------------
        // thread (wo = tid>>3, sub = tid&7): sums replicas r == sub (mod 8)
        // for word w; 8-lane butterfly gives the full 256-replica sum.
        {
            const int sub = tid & 7, wo = tid >> 3;
            const bool last = (it == 2);
            for (int base = blockIdx.x * (BS / 8); base < nwords;
                 base += GRID * (BS / 8)) {
                int w = base + wo;                    // uniform per 8-lane group
                u32 slo = 0, shi = 0;
                if (w < nwords) {
#pragma unroll 4
                    for (int j = 0; j < RPQ; ++j) {
                        u32 v = Trep[(size_t)(sub + NXCD * j) * nwords + w];
                        slo += v & 0xffffu;
                        shi += v >> 16;
                    }
                }
#pragma unroll
                for (int d = 1; d < 8; d <<= 1) {
                    slo += __shfl_xor(slo, d);
                    shi += __shfl_xor(shi, d);
                }
                if (w < nwords && sub < 2) {
                    int l = 2 * w + sub;
                    if (l < n_links) {
                        float T   = (float)(sub ? shi : slo) * (1.0f / TSCALE);
                        float cap = L[l] * (1.0f / 1000.0f);
                        float rho = T / cap;
                        float r2 = rho * rho, r4 = r2 * r2, r8 = r4 * r4;
                        float r16 = r8 * r8, r32 = r16 * r16, r33 = r32 * rho;
                        if (!last) {
                            float bp = (1.0f - rho) * r32 / (1.0f - r33 + 1e-8f);
                            u32 b = __float2uint_rn(bp * 256.0f);
                            bpq[l] = (u8)(b > 255u ? 255u : b);
                        } else {
                            float pi0 = (1.0f - rho) / (1.0f - r33);  // no eps (ref)
                            float S = 1.0f, rp = 1.0f;
#pragma unroll
                            for (int m = 1; m <= 32; ++m) { rp *= rho; S += (float)m * rp; }
                            float Lq = pi0 * S * (1.0f / 32.0f);
                            float X  = Lq * 32000.0f / L[l];
                            u32 xf = __float2uint_rn(X * XSCALE);
                            xq[l] = (u16)(xf > 65535u ? 65535u : xf);
                            out_links[3 * l + 0] = Lq;
                            out_links[3 * l + 1] = rho;
                            out_links[3 * l + 2] = pi0 * r32;
                        }
                    }
                }
            }
        }
        grid.sync();    // bpq (iters 0,1) / xq+outputs (iter 2) visible
    }

    // ---------------- gather: X_l table in LDS, edges from registers -------
    u16* xl = (u16*)h;                                // alias histogram space
    for (int i = tid; i < n_links; i += BS) xl[i] = xq[i];
    __syncthreads();
    if (act) {
        u32 s0 = 0, s1 = 0, s2 = 0, s3 = 0;
#pragma unroll
        for (int k = 0; k < KHOPS; ++k) {
            s0 += xl[ep[k].x & 0xffffu];
            s1 += xl[ep[k].x >> 16];
            s2 += xl[ep[k].y & 0xffffu];
            s3 += xl[ep[k].y >> 16];
        }
        *(float4*)&res[p] = make_float4((float)s0 * (1.0f / XSCALE),
                                        (float)s1 * (1.0f / XSCALE),
                                        (float)s2 * (1.0f / XSCALE),
                                        (float)s3 * (1.0f / XSCALE));
    }
}

// ---------------------------------------------------------------------------
extern "C" void kernel_launch(void* const* d_in, const int* in_sizes, int n_in,
                              void* d_out, int out_size, void* d_ws, size_t ws_size,
                              hipStream_t stream) {
    const float* P        = (const float*)d_in[0];   // (n_paths, 3)
    const float* L        = (const float*)d_in[1];   // (n_links, 1)
    const int*   pl_edges = (const int*)d_in[3];     // (KHOPS, n_paths)

    const int n_paths = in_sizes[0] / 3;
    const int n_links = in_sizes[1];
    const int nwords  = (n_links + 1) / 2;

    // ws layout: Trep (GRID*nwords u32) | bpq (u8) | xq (u16)
    char* w = (char*)d_ws;
    u32* Trep = (u32*)w;                      w += (size_t)GRID * nwords * 4;
    u8*  bpq  = (u8*)w;                       w += (size_t)n_links;
    w = (char*)(((size_t)w + 15) & ~15ull);
    u16* xq   = (u16*)w;

    float* res       = (float*)d_out;                // (n_paths,)
    float* out_links = res + n_paths;                // (n_links, 3)

    void* args[] = {
        (void*)&P, (void*)&L, (void*)&pl_edges,
        (void*)&Trep, (void*)&bpq, (void*)&xq,
        (void*)&res, (void*)&out_links,
        (void*)&n_paths, (void*)&n_links, (void*)&nwords,
    };
    hipLaunchCooperativeKernel((const void*)fused_kernel,
                               dim3(GRID), dim3(BS), args, 0, stream);
}

// Round 2
// 182.977 us; speedup vs baseline: 2.2057x; 2.2057x over previous
//
#include <hip/hip_runtime.h>

#define KHOPS  8
#define BS     1024            // scatter/gather/merge block size
#define MAXL   50176           // max links (LDS tables sized for this)
#define HWORDS (MAXL / 2)      // 25088 u32 words = 100352 B (u16-pair histogram)
#define GRID   256             // scatter grid: 1 block/CU
#define NXCD   8
#define RPQ    (GRID / NXCD)   // replicas per butterfly sub-lane = 32
#define TSCALE  2048.0f        // traffic deposit fixed-point scale (Q11)
#define XSCALE  131072.0f      // X_l fixed-point scale (Q17; X < 0.5 guaranteed)

typedef unsigned char  u8;
typedef unsigned short u16;
typedef unsigned int   u32;

// ---------------------------------------------------------------------------
// deposit helper: packed u16-pair histogram, ds_add_u32
// ---------------------------------------------------------------------------
__device__ __forceinline__ void deposit(u32* h, u32 link, float t) {
    atomicAdd(&h[link >> 1], __float2uint_rn(t * TSCALE) << ((link & 1) << 4));
}

// ---------------------------------------------------------------------------
// scatter, iteration 1 (fused convert): reads raw int edges + P, converts to
// packed u16 (writes e16 for later passes) and compact A; bp == 0.5 constant.
// Single full-size histogram (100 KB LDS), 4 paths/thread.
// ---------------------------------------------------------------------------
__global__ __launch_bounds__(BS) void scatter_first(
        const float* __restrict__ P,         // (n_paths,3)
        const int*   __restrict__ pl_edges,  // (KHOPS,n_paths)
        u16*   __restrict__ e16,             // out: packed link ids
        float* __restrict__ A,               // out: compact traffic source
        u32*   __restrict__ Trep,            // [GRID][nwords]
        int n_paths, int nwords) {
    __shared__ u32 h[HWORDS];
    const int tid = threadIdx.x;
    const int nthreads = gridDim.x * BS;

    for (int i = tid; i < HWORDS; i += BS) h[i] = 0u;
    __syncthreads();

    for (int p = (blockIdx.x * BS + tid) * 4; p < n_paths; p += 4 * nthreads) {
        uint2 ep[KHOPS];
#pragma unroll
        for (int k = 0; k < KHOPS; ++k) {
            int4 e4 = *(const int4*)&pl_edges[k * n_paths + p];   // coalesced
            ep[k].x = (u32)(e4.x - n_paths) | ((u32)(e4.y - n_paths) << 16);
            ep[k].y = (u32)(e4.z - n_paths) | ((u32)(e4.w - n_paths) << 16);
            *(uint2*)&e16[k * n_paths + p] = ep[k];               // coalesced
        }
        float4 q0 = *(const float4*)&P[3 * p];       // A = P[:,1]
        float4 q1 = *(const float4*)&P[3 * p + 4];
        float4 q2 = *(const float4*)&P[3 * p + 8];
        float t0 = q0.y, t1 = q1.x, t2 = q1.w, t3 = q2.z;
        *(float4*)&A[p] = make_float4(t0, t1, t2, t3);
#pragma unroll
        for (int k = 0; k < KHOPS; ++k) {
            deposit(h, ep[k].x & 0xffffu, t0);
            deposit(h, ep[k].x >> 16,     t1);
            deposit(h, ep[k].y & 0xffffu, t2);
            deposit(h, ep[k].y >> 16,     t3);
            t0 *= 0.5f; t1 *= 0.5f; t2 *= 0.5f; t3 *= 0.5f;
        }
    }
    __syncthreads();

    u32* Tmine = Trep + (size_t)blockIdx.x * nwords;
    for (int i = tid; i < nwords; i += BS) Tmine[i] = h[i];
}

// ---------------------------------------------------------------------------
// scatter, iterations 2+: bp table in LDS as u8 Q8 (50 KB) + full histogram
// (100 KB) = 147 KB -> single chunk, 1 block/CU.
// ---------------------------------------------------------------------------
__global__ __launch_bounds__(BS) void scatter_rest(
        const float* __restrict__ A,
        const u16*   __restrict__ e16,
        const u8*    __restrict__ bpq,       // (n_links) Q8
        u32*         __restrict__ Trep,
        int n_paths, int n_links, int nwords) {
    __shared__ u8  bpl[MAXL];                // 50176 B
    __shared__ u32 h[HWORDS];                // 100352 B
    const int tid = threadIdx.x;
    const int nthreads = gridDim.x * BS;

    for (int i = tid; i < n_links; i += BS) bpl[i] = bpq[i];
    for (int i = tid; i < HWORDS; i += BS) h[i] = 0u;
    __syncthreads();

    for (int p = (blockIdx.x * BS + tid) * 4; p < n_paths; p += 4 * nthreads) {
        uint2 ep[KHOPS];
#pragma unroll
        for (int k = 0; k < KHOPS; ++k)
            ep[k] = *(const uint2*)&e16[k * n_paths + p];
        float4 a = *(const float4*)&A[p];
        float t0 = a.x, t1 = a.y, t2 = a.z, t3 = a.w;
#pragma unroll
        for (int k = 0; k < KHOPS; ++k) {
            u32 l0 = ep[k].x & 0xffffu, l1 = ep[k].x >> 16;
            u32 l2 = ep[k].y & 0xffffu, l3 = ep[k].y >> 16;
            deposit(h, l0, t0);
            deposit(h, l1, t1);
            deposit(h, l2, t2);
            deposit(h, l3, t3);
            t0 *= (float)(256 - (int)bpl[l0]) * (1.0f / 256.0f);
            t1 *= (float)(256 - (int)bpl[l1]) * (1.0f / 256.0f);
            t2 *= (float)(256 - (int)bpl[l2]) * (1.0f / 256.0f);
            t3 *= (float)(256 - (int)bpl[l3]) * (1.0f / 256.0f);
        }
    }
    __syncthreads();

    u32* Tmine = Trep + (size_t)blockIdx.x * nwords;
    for (int i = tid; i < nwords; i += BS) Tmine[i] = h[i];
}

// ---------------------------------------------------------------------------
// fused merge + link update: each 8-lane group owns one histogram word
// (= 2 links).  Lane `sub` sums replicas r == sub (mod 8); an 8-lane
// __shfl_xor butterfly yields the full 256-replica integer sum (bit-identical
// to the old merge->partial->link chain).  Lanes sub<2 then run the link
// math inline: bp (Q8) on early iterations, full epilogue on the last.
// Removes the partial[] round trip and 3 dispatches.
// ---------------------------------------------------------------------------
__global__ __launch_bounds__(BS) void mergelink_kernel(
        const u32*   __restrict__ Trep,
        const float* __restrict__ L,
        u8*          __restrict__ bpq,
        u16*         __restrict__ xq,
        float*       __restrict__ out_links,
        int n_links, int nwords, int last) {
    const int sub = threadIdx.x & 7;
    const int wo  = threadIdx.x >> 3;
    const int w   = blockIdx.x * (BS / 8) + wo;

    u32 slo = 0, shi = 0;
    if (w < nwords) {
#pragma unroll 4
        for (int j = 0; j < RPQ; ++j) {
            u32 v = Trep[(size_t)(sub + NXCD * j) * nwords + w];
            slo += v & 0xffffu;
            shi += v >> 16;
        }
    }
#pragma unroll
    for (int d = 1; d < 8; d <<= 1) {
        slo += __shfl_xor(slo, d);
        shi += __shfl_xor(shi, d);
    }
    if (w < nwords && sub < 2) {
        int l = 2 * w + sub;
        if (l < n_links) {
            float T   = (float)(sub ? shi : slo) * (1.0f / TSCALE);
            float cap = L[l] * (1.0f / 1000.0f);
            float rho = T / cap;
            float r2 = rho * rho, r4 = r2 * r2, r8 = r4 * r4, r16 = r8 * r8;
            float r32 = r16 * r16, r33 = r32 * rho;
            if (!last) {
                float bp = (1.0f - rho) * r32 / (1.0f - r33 + 1e-8f);
                u32 b = __float2uint_rn(bp * 256.0f);
                bpq[l] = (u8)(b > 255u ? 255u : b);
            } else {
                float pi0 = (1.0f - rho) / (1.0f - r33);     // no epsilon (ref)
                float S = 1.0f, rp = 1.0f;
#pragma unroll
                for (int m = 1; m <= 32; ++m) { rp *= rho; S += (float)m * rp; }
                float Lq = pi0 * S * (1.0f / 32.0f);
                float X  = Lq * 32000.0f / L[l];
                u32 xf = __float2uint_rn(X * XSCALE);
                xq[l] = (u16)(xf > 65535u ? 65535u : xf);
                out_links[3 * l + 0] = Lq;
                out_links[3 * l + 1] = rho;
                out_links[3 * l + 2] = pi0 * r32;
            }
        }
    }
}

// ---------------------------------------------------------------------------
// gather: X_l table in LDS (Q17 u16); integer per-path sum, 4 paths/thread.
// ---------------------------------------------------------------------------
__global__ __launch_bounds__(BS) void gather_kernel(
        const u16* __restrict__ e16,
        const u16* __restrict__ xq,
        float*     __restrict__ res,
        int n_paths, int n_links) {
    __shared__ u16 xl[MAXL];
    const int tid = threadIdx.x;
    for (int i = tid; i < n_links; i += BS) xl[i] = xq[i];
    __syncthreads();

    const int nthreads = gridDim.x * BS;
    for (int p = (blockIdx.x * BS + tid) * 4; p < n_paths; p += 4 * nthreads) {
        u32 s0 = 0, s1 = 0, s2 = 0, s3 = 0;
#pragma unroll
        for (int k = 0; k < KHOPS; ++k) {
            uint2 ep = *(const uint2*)&e16[k * n_paths + p];
            s0 += xl[ep.x & 0xffffu];
            s1 += xl[ep.x >> 16];
            s2 += xl[ep.y & 0xffffu];
            s3 += xl[ep.y >> 16];
        }
        *(float4*)&res[p] = make_float4((float)s0 * (1.0f / XSCALE),
                                        (float)s1 * (1.0f / XSCALE),
                                        (float)s2 * (1.0f / XSCALE),
                                        (float)s3 * (1.0f / XSCALE));
    }
}

// ---------------------------------------------------------------------------
extern "C" void kernel_launch(void* const* d_in, const int* in_sizes, int n_in,
                              void* d_out, int out_size, void* d_ws, size_t ws_size,
                              hipStream_t stream) {
    const float* P        = (const float*)d_in[0];   // (n_paths, 3)
    const float* L        = (const float*)d_in[1];   // (n_links, 1)
    const int*   pl_edges = (const int*)d_in[3];     // (KHOPS, n_paths)

    const int n_paths = in_sizes[0] / 3;
    const int n_links = in_sizes[1];
    const int n_edges = KHOPS * n_paths;
    const int nwords  = (n_links + 1) / 2;

    // ws layout: e16 | A | bpq(u8) | xq(u16) | Trep
    char* w = (char*)d_ws;
    u16*   e16 = (u16*)w;                     w += (size_t)n_edges * 2;
    w = (char*)(((size_t)w + 15) & ~15ull);
    float* A   = (float*)w;                   w += (size_t)n_paths * 4;
    u8*    bpq = (u8*)w;                      w += (size_t)n_links;
    w = (char*)(((size_t)w + 15) & ~15ull);
    u16*   xq  = (u16*)w;                     w += (size_t)n_links * 2;
    w = (char*)(((size_t)w + 15) & ~15ull);
    u32*   Trep = (u32*)w;                    // GRID*nwords*4 = 25.6 MB

    float* res       = (float*)d_out;                // (n_paths,)
    float* out_links = res + n_paths;                // (n_links, 3)

    const int gm = (nwords + (BS / 8) - 1) / (BS / 8);   // 8-lane group per word

    for (int it = 0; it < 3; ++it) {
        if (it == 0)
            scatter_first<<<GRID, BS, 0, stream>>>(P, pl_edges, e16, A, Trep,
                                                   n_paths, nwords);
        else
            scatter_rest<<<GRID, BS, 0, stream>>>(A, e16, bpq, Trep,
                                                  n_paths, n_links, nwords);
        mergelink_kernel<<<gm, BS, 0, stream>>>(Trep, L, bpq, xq, out_links,
                                                n_links, nwords,
                                                it == 2 ? 1 : 0);
    }
    gather_kernel<<<GRID, BS, 0, stream>>>(e16, xq, res, n_paths, n_links);
}

// Round 4
// 169.366 us; speedup vs baseline: 2.3829x; 1.0804x over previous
//
#include <hip/hip_runtime.h>

#define KHOPS  8
#define BS     1024            // scatter/gather/merge block size
#define MAXL   50176           // max links (LDS tables sized for this)
#define HWORDS (MAXL / 2)      // 25088 u32 words = 100352 B (u16-pair histogram)
#define GRID   256             // scatter grid: 1 block/CU
#define NXCD   8               // merge groups == XCD count
#define RPQ    (GRID / NXCD)   // replicas per merge group = 32
#define TSCALE  2048.0f        // traffic deposit fixed-point scale (Q11)
#define XSCALE  131072.0f      // X_l fixed-point scale (Q17; X < 0.5 guaranteed)

typedef unsigned char  u8;
typedef unsigned short u16;
typedef unsigned int   u32;

// ---------------------------------------------------------------------------
// deposit helper: packed u16-pair histogram, ds_add_u32
// ---------------------------------------------------------------------------
__device__ __forceinline__ void deposit(u32* h, u32 link, float t) {
    atomicAdd(&h[link >> 1], __float2uint_rn(t * TSCALE) << ((link & 1) << 4));
}

// ---------------------------------------------------------------------------
// scatter, iteration 1 (fused convert): reads raw int edges + P, converts to
// packed u16 (writes e16 for later passes) and compact A; bp == 0.5 constant.
// Single full-size histogram (100 KB LDS), 4 paths/thread.
// ---------------------------------------------------------------------------
__global__ __launch_bounds__(BS) void scatter_first(
        const float* __restrict__ P,         // (n_paths,3)
        const int*   __restrict__ pl_edges,  // (KHOPS,n_paths)
        u16*   __restrict__ e16,             // out: packed link ids
        float* __restrict__ A,               // out: compact traffic source
        u32*   __restrict__ Trep,            // [GRID][nwords]
        int n_paths, int nwords) {
    __shared__ u32 h[HWORDS];
    const int tid = threadIdx.x;
    const int nthreads = gridDim.x * BS;

    // zero histogram with ds_write_b128 (HWORDS % 4 == 0)
    for (int i = tid; i < (HWORDS >> 2); i += BS)
        ((uint4*)h)[i] = make_uint4(0u, 0u, 0u, 0u);
    __syncthreads();

    for (int p = (blockIdx.x * BS + tid) * 4; p < n_paths; p += 4 * nthreads) {
        uint2 ep[KHOPS];
#pragma unroll
        for (int k = 0; k < KHOPS; ++k) {
            int4 e4 = *(const int4*)&pl_edges[k * n_paths + p];   // coalesced
            ep[k].x = (u32)(e4.x - n_paths) | ((u32)(e4.y - n_paths) << 16);
            ep[k].y = (u32)(e4.z - n_paths) | ((u32)(e4.w - n_paths) << 16);
            *(uint2*)&e16[k * n_paths + p] = ep[k];               // coalesced
        }
        float4 q0 = *(const float4*)&P[3 * p];       // A = P[:,1]
        float4 q1 = *(const float4*)&P[3 * p + 4];
        float4 q2 = *(const float4*)&P[3 * p + 8];
        float t0 = q0.y, t1 = q1.x, t2 = q1.w, t3 = q2.z;
        *(float4*)&A[p] = make_float4(t0, t1, t2, t3);
#pragma unroll
        for (int k = 0; k < KHOPS; ++k) {
            deposit(h, ep[k].x & 0xffffu, t0);
            deposit(h, ep[k].x >> 16,     t1);
            deposit(h, ep[k].y & 0xffffu, t2);
            deposit(h, ep[k].y >> 16,     t3);
            t0 *= 0.5f; t1 *= 0.5f; t2 *= 0.5f; t3 *= 0.5f;
        }
    }
    __syncthreads();

    // flush with ds_read_b128 + global_store_dwordx4
    u32* Tmine = Trep + (size_t)blockIdx.x * nwords;
    const int nw4 = nwords >> 2;
    for (int i = tid; i < nw4; i += BS)
        ((uint4*)Tmine)[i] = ((const uint4*)h)[i];
    for (int i = (nw4 << 2) + tid; i < nwords; i += BS) Tmine[i] = h[i];
}

// ---------------------------------------------------------------------------
// scatter, iterations 2+: bp table in LDS as u8 Q8 (50 KB) + full histogram
// (100 KB) = 147 KB -> single chunk, 1 block/CU.
// ---------------------------------------------------------------------------
__global__ __launch_bounds__(BS) void scatter_rest(
        const float* __restrict__ A,
        const u16*   __restrict__ e16,
        const u8*    __restrict__ bpq,       // (n_links) Q8, 16B-aligned
        u32*         __restrict__ Trep,
        int n_paths, int n_links, int nwords) {
    __shared__ u8  bpl[MAXL];                // 50176 B
    __shared__ u32 h[HWORDS];                // 100352 B
    const int tid = threadIdx.x;
    const int nthreads = gridDim.x * BS;

    // stage bp table with 16B loads/stores (tail loop covers remainder)
    const int nb16 = n_links >> 4;
    for (int i = tid; i < nb16; i += BS)
        ((uint4*)bpl)[i] = ((const uint4*)bpq)[i];
    for (int i = (nb16 << 4) + tid; i < n_links; i += BS) bpl[i] = bpq[i];
    for (int i = tid; i < (HWORDS >> 2); i += BS)
        ((uint4*)h)[i] = make_uint4(0u, 0u, 0u, 0u);
    __syncthreads();

    for (int p = (blockIdx.x * BS + tid) * 4; p < n_paths; p += 4 * nthreads) {
        uint2 ep[KHOPS];
#pragma unroll
        for (int k = 0; k < KHOPS; ++k)
            ep[k] = *(const uint2*)&e16[k * n_paths + p];
        float4 a = *(const float4*)&A[p];
        float t0 = a.x, t1 = a.y, t2 = a.z, t3 = a.w;
#pragma unroll
        for (int k = 0; k < KHOPS; ++k) {
            u32 l0 = ep[k].x & 0xffffu, l1 = ep[k].x >> 16;
            u32 l2 = ep[k].y & 0xffffu, l3 = ep[k].y >> 16;
            deposit(h, l0, t0);
            deposit(h, l1, t1);
            deposit(h, l2, t2);
            deposit(h, l3, t3);
            t0 *= (float)(256 - (int)bpl[l0]) * (1.0f / 256.0f);
            t1 *= (float)(256 - (int)bpl[l1]) * (1.0f / 256.0f);
            t2 *= (float)(256 - (int)bpl[l2]) * (1.0f / 256.0f);
            t3 *= (float)(256 - (int)bpl[l3]) * (1.0f / 256.0f);
        }
    }
    __syncthreads();

    u32* Tmine = Trep + (size_t)blockIdx.x * nwords;
    const int nw4 = nwords >> 2;
    for (int i = tid; i < nw4; i += BS)
        ((uint4*)Tmine)[i] = ((const uint4*)h)[i];
    for (int i = (nw4 << 2) + tid; i < nwords; i += BS) Tmine[i] = h[i];
}

// ---------------------------------------------------------------------------
// merge: group q sums replicas r == q (mod 8). Replica r was written by
// scatter block r on XCD r%8; merge block has q = blockIdx.x & 7 -> same XCD
// -> L2-local reads (32 x 100 KB = 3.2 MB fits the 4 MB XCD L2).
// Vectorized: each thread owns a PAIR of histogram words (uint2 load,
// 512 B/wave-inst coalesced) and stores 4 link sums as one uint4.
// Bit-identical u32 arithmetic to the verified scalar merge.
// ---------------------------------------------------------------------------
__global__ __launch_bounds__(BS) void merge_kernel(
        const u32* __restrict__ Trep,
        u32* __restrict__ partial,           // [NXCD][n_links]
        int n_links, int nwords) {
    const int q  = blockIdx.x & (NXCD - 1);
    const int p2 = (blockIdx.x >> 3) * BS + threadIdx.x;   // word-pair index
    const int npairs = nwords >> 1;
    if (p2 >= npairs) return;
    u32 s0 = 0, s1 = 0, s2 = 0, s3 = 0;    // lo0, hi0, lo1, hi1
#pragma unroll 4
    for (int j = 0; j < RPQ; ++j) {
        uint2 v = *(const uint2*)&Trep[(size_t)(q + NXCD * j) * nwords + 2 * p2];
        s0 += v.x & 0xffffu;  s1 += v.x >> 16;
        s2 += v.y & 0xffffu;  s3 += v.y >> 16;
    }
    *(uint4*)&partial[(size_t)q * n_links + 4 * p2] = make_uint4(s0, s1, s2, s3);
}

// ---------------------------------------------------------------------------
// link update: T = (sum of 8 integer partials)/TSCALE; rho; writes bp (Q8)
// on early iterations, full epilogue (outputs + xq) on the last.
// ---------------------------------------------------------------------------
__global__ void link_update_kernel(const float* __restrict__ L,
                                   const u32*   __restrict__ partial,
                                   u8*          __restrict__ bpq,
                                   u16*         __restrict__ xq,
                                   float*       __restrict__ out_links,
                                   int n_links, int last) {
    int l = blockIdx.x * blockDim.x + threadIdx.x;
    if (l >= n_links) return;
    u32 s = 0;
#pragma unroll
    for (int q = 0; q < NXCD; ++q)
        s += partial[(size_t)q * n_links + l];
    float T   = (float)s * (1.0f / TSCALE);
    float cap = L[l] * (1.0f / 1000.0f);
    float rho = T / cap;
    float r2 = rho * rho, r4 = r2 * r2, r8 = r4 * r4, r16 = r8 * r8;
    float r32 = r16 * r16, r33 = r32 * rho;
    if (!last) {
        float bp = (1.0f - rho) * r32 / (1.0f - r33 + 1e-8f);
        u32 b = __float2uint_rn(bp * 256.0f);
        bpq[l] = (u8)(b > 255u ? 255u : b);
    } else {
        float pi0 = (1.0f - rho) / (1.0f - r33);     // no epsilon (ref)
        float S = 1.0f, rp = 1.0f;
#pragma unroll
        for (int m = 1; m <= 32; ++m) { rp *= rho; S += (float)m * rp; }
        float Lq = pi0 * S * (1.0f / 32.0f);
        float X  = Lq * 32000.0f / L[l];
        u32 xf = __float2uint_rn(X * XSCALE);
        xq[l] = (u16)(xf > 65535u ? 65535u : xf);
        out_links[3 * l + 0] = Lq;
        out_links[3 * l + 1] = rho;
        out_links[3 * l + 2] = pi0 * r32;
    }
}

// ---------------------------------------------------------------------------
// gather: X_l table in LDS (Q17 u16); integer per-path sum, 4 paths/thread.
// ---------------------------------------------------------------------------
__global__ __launch_bounds__(BS) void gather_kernel(
        const u16* __restrict__ e16,
        const u16* __restrict__ xq,          // 16B-aligned
        float*     __restrict__ res,
        int n_paths, int n_links) {
    __shared__ u16 xl[MAXL];
    const int tid = threadIdx.x;
    const int nx8 = n_links >> 3;            // 8 u16 per uint4
    for (int i = tid; i < nx8; i += BS)
        ((uint4*)xl)[i] = ((const uint4*)xq)[i];
    for (int i = (nx8 << 3) + tid; i < n_links; i += BS) xl[i] = xq[i];
    __syncthreads();

    const int nthreads = gridDim.x * BS;
    for (int p = (blockIdx.x * BS + tid) * 4; p < n_paths; p += 4 * nthreads) {
        u32 s0 = 0, s1 = 0, s2 = 0, s3 = 0;
#pragma unroll
        for (int k = 0; k < KHOPS; ++k) {
            uint2 ep = *(const uint2*)&e16[k * n_paths + p];
            s0 += xl[ep.x & 0xffffu];
            s1 += xl[ep.x >> 16];
            s2 += xl[ep.y & 0xffffu];
            s3 += xl[ep.y >> 16];
        }
        *(float4*)&res[p] = make_float4((float)s0 * (1.0f / XSCALE),
                                        (float)s1 * (1.0f / XSCALE),
                                        (float)s2 * (1.0f / XSCALE),
                                        (float)s3 * (1.0f / XSCALE));
    }
}

// ---------------------------------------------------------------------------
extern "C" void kernel_launch(void* const* d_in, const int* in_sizes, int n_in,
                              void* d_out, int out_size, void* d_ws, size_t ws_size,
                              hipStream_t stream) {
    const float* P        = (const float*)d_in[0];   // (n_paths, 3)
    const float* L        = (const float*)d_in[1];   // (n_links, 1)
    const int*   pl_edges = (const int*)d_in[3];     // (KHOPS, n_paths)

    const int n_paths = in_sizes[0] / 3;
    const int n_links = in_sizes[1];
    const int n_edges = KHOPS * n_paths;
    const int nwords  = (n_links + 1) / 2;

    // ws layout: e16 | A | bpq(u8) | xq(u16) | partial (u32 NXCD*nl) | Trep
    char* w = (char*)d_ws;
    u16*   e16 = (u16*)w;                     w += (size_t)n_edges * 2;
    w = (char*)(((size_t)w + 15) & ~15ull);
    float* A   = (float*)w;                   w += (size_t)n_paths * 4;
    u8*    bpq = (u8*)w;                      w += (size_t)n_links;
    w = (char*)(((size_t)w + 15) & ~15ull);
    u16*   xq  = (u16*)w;                     w += (size_t)n_links * 2;
    w = (char*)(((size_t)w + 15) & ~15ull);
    u32* partial = (u32*)w;                   w += (size_t)NXCD * n_links * 4;
    u32* Trep    = (u32*)w;                   // GRID*nwords*4 = 25.6 MB

    float* res       = (float*)d_out;                // (n_paths,)
    float* out_links = res + n_paths;                // (n_links, 3)

    const int bs = 256;
    const int gl = (n_links + bs - 1) / bs;
    const int npairs = nwords >> 1;
    const int gm = NXCD * ((npairs + BS - 1) / BS);  // XCD-aligned merge grid

    for (int it = 0; it < 3; ++it) {
        if (it == 0)
            scatter_first<<<GRID, BS, 0, stream>>>(P, pl_edges, e16, A, Trep,
                                                   n_paths, nwords);
        else
            scatter_rest<<<GRID, BS, 0, stream>>>(A, e16, bpq, Trep,
                                                  n_paths, n_links, nwords);
        merge_kernel<<<gm, BS, 0, stream>>>(Trep, partial, n_links, nwords);
        link_update_kernel<<<gl, bs, 0, stream>>>(L, partial, bpq, xq,
                                                  out_links, n_links,
                                                  it == 2 ? 1 : 0);
    }
    gather_kernel<<<GRID, BS, 0, stream>>>(e16, xq, res, n_paths, n_links);
}